// Round 18
// baseline (113.315 us; speedup 1.0000x reference)
//
#include <hip/hip_runtime.h>
#include <hip/hip_bf16.h>
#include <cstdint>
#include <cstddef>

#define NG 32
#define NP 64
#define ND 512
#define HW 192
#define KT16 16  // BK=32 K-tiles
#define EPSV 1e-5f

typedef _Float16 half8 __attribute__((ext_vector_type(8)));
typedef float floatx4 __attribute__((ext_vector_type(4)));

// ---- pre-pass: src[b][d][x] f32 -> T5[b][kt][rb][l][j] fp16 for 16x16x32 frags.
// h = rb*64 + l (rb: 16-row block 0..11); element j: row = rb*16 + (l&15),
// d = kt*32 + (l>>4)*8 + j.  A 16x16x32 frag = 1KB contiguous (lane*16B);
// a BK=32 tile (A or B) = 12KB linear -> staging is a pure linear copy.
__global__ __launch_bounds__(256) void prep_frag5(const float* __restrict__ gal,
                                                  const float* __restrict__ prob,
                                                  _Float16* __restrict__ galT5,
                                                  _Float16* __restrict__ probT5) {
  __shared__ float lds[32 * 192];  // 24KB
  const int z = blockIdx.x;   // 0..95: first NP probes, then NG gals
  const int kt = blockIdx.y;  // 0..15
  const float* src;
  _Float16* dst;
  if (z < NP) {
    src = prob + (size_t)z * ND * HW;
    dst = probT5 + (size_t)z * 98304;
  } else {
    src = gal + (size_t)(z - NP) * ND * HW;
    dst = galT5 + (size_t)(z - NP) * 98304;
  }
  src += (size_t)kt * 32 * HW;
  dst += (size_t)kt * 6144;
  const int t = threadIdx.x;
#pragma unroll
  for (int i = 0; i < 24; ++i) lds[i * 256 + t] = src[i * 256 + t];
  __syncthreads();
#pragma unroll
  for (int r = 0; r < 3; ++r) {
    const int h = r * 256 + t;  // 768 slots
    const int rb = h >> 6, l = h & 63;
    const int row = rb * 16 + (l & 15), dk = (l >> 4) * 8;
    half8 v;
#pragma unroll
    for (int j = 0; j < 8; ++j) v[j] = (_Float16)lds[(dk + j) * 192 + row];
    *(half8*)(dst + (size_t)h * 8) = v;
  }
}

// ---- async 16B global -> LDS
__device__ __forceinline__ void g2l16(const void* g, void* l) {
  __builtin_amdgcn_global_load_lds(
      (const __attribute__((address_space(1))) void*)g,
      (__attribute__((address_space(3))) void*)l, 16, 0, 0);
}

// ---- main fused kernel: one WG (512 thr, 8 waves) per (g,p) pair ----
// Wave grid 4(wr) x 2(wc); wave tile 48x96 via 3x6 frags of
// mfma_f32_16x16x32_f16 -> acc only 72 regs/wave; __launch_bounds__(512,4)
// targets <=128 unified regs = 4 waves/SIMD = 16 waves/CU (2 antiphase
// blocks) -- double R16's TLP to fill phase-latency slack.  BK=32 triple-
// buffered LDS (72KB tiles), counted vmcnt(3) keeps stage(kt+2) in flight;
// R16's rigid 2-barrier phase (it beat the loose R17 interleave).
__global__ __launch_bounds__(512, 4) void qaconv_main(
    const _Float16* __restrict__ galT5, const _Float16* __restrict__ probT5,
    const float* __restrict__ bn_w, const float* __restrict__ bn_b,
    const float* __restrict__ bn_m, const float* __restrict__ bn_v,
    const float* __restrict__ fc_w, const float* __restrict__ fc_b,
    const float* __restrict__ lbn_w, const float* __restrict__ lbn_b,
    const float* __restrict__ lbn_m, const float* __restrict__ lbn_v,
    float* __restrict__ out) {
  __shared__ __align__(16) char tiles[3][24576];  // [buf][A 12KB | B 12KB]
  __shared__ float colp[4][HW];
  __shared__ float rowpart[2][HW];
  __shared__ float wsum[8];

  const int bid = blockIdx.x;
  const int g = bid >> 6, p = bid & 63;

  const int t = threadIdx.x;
  const int lane = t & 63, wid = t >> 6;  // wid 0..7
  const int wr = wid & 3;                 // probe-row group (48 rows)
  const int wc = wid >> 2;                // gal-col half (96 cols)
  const int l15 = lane & 15, lhi = lane >> 4;

  // staging sources: thread covers slots {r*512 + wid*64 + lane}, slot<768 = A.
  const _Float16* pAt = probT5 + (size_t)p * 98304 + lane * 8;
  const _Float16* pBt = galT5 + (size_t)g * 98304 + lane * 8;

  floatx4 acc[3][6];
#pragma unroll
  for (int ii = 0; ii < 3; ++ii)
#pragma unroll
    for (int jj = 0; jj < 6; ++jj) acc[ii][jj] = (floatx4){0.f, 0.f, 0.f, 0.f};

  half8 af[3], bf[6];

#define STAGE(kt_, base_)                                                      \
  {                                                                            \
    _Pragma("unroll") for (int r_ = 0; r_ < 3; ++r_) {                         \
      const int s0_ = r_ * 512 + wid * 64;                                     \
      const _Float16* s_ = (s0_ < 768)                                         \
                               ? (pAt + (size_t)(kt_)*6144 + (size_t)s0_ * 8)  \
                               : (pBt + (size_t)(kt_)*6144 + (size_t)(s0_ - 768) * 8); \
      g2l16(s_, (char*)(base_) + s0_ * 16);                                    \
    }                                                                          \
  }

#define READ9(base_)                                                           \
  {                                                                            \
    const char* bA_ = (const char*)(base_);                                    \
    const char* bB_ = (const char*)(base_) + 12288;                            \
    af[0] = *(const half8*)(bA_ + (wr * 3 + 0) * 1024 + lane * 16);            \
    af[1] = *(const half8*)(bA_ + (wr * 3 + 1) * 1024 + lane * 16);            \
    af[2] = *(const half8*)(bA_ + (wr * 3 + 2) * 1024 + lane * 16);            \
    bf[0] = *(const half8*)(bB_ + (wc * 6 + 0) * 1024 + lane * 16);            \
    bf[1] = *(const half8*)(bB_ + (wc * 6 + 1) * 1024 + lane * 16);            \
    bf[2] = *(const half8*)(bB_ + (wc * 6 + 2) * 1024 + lane * 16);            \
    bf[3] = *(const half8*)(bB_ + (wc * 6 + 3) * 1024 + lane * 16);            \
    bf[4] = *(const half8*)(bB_ + (wc * 6 + 4) * 1024 + lane * 16);            \
    bf[5] = *(const half8*)(bB_ + (wc * 6 + 5) * 1024 + lane * 16);            \
  }

#define MFMA18()                                                               \
  {                                                                            \
    __builtin_amdgcn_s_setprio(1);                                             \
    _Pragma("unroll") for (int ii = 0; ii < 3; ++ii)                           \
        _Pragma("unroll") for (int jj = 0; jj < 6; ++jj)                       \
            acc[ii][jj] = __builtin_amdgcn_mfma_f32_16x16x32_f16(af[ii], bf[jj],\
                                                                 acc[ii][jj], 0, 0, 0); \
    __builtin_amdgcn_s_setprio(0);                                             \
  }

#define SLOT(kt_, rdb_, stb_, doStage_, vmW_)                \
  {                                                          \
    READ9(rdb_)                                              \
    if (doStage_) STAGE((kt_) + 2, stb_)                     \
    __builtin_amdgcn_sched_barrier(0);                       \
    __builtin_amdgcn_s_barrier();                            \
    asm volatile("s_waitcnt lgkmcnt(0)" ::: "memory");       \
    __builtin_amdgcn_sched_barrier(0);                       \
    MFMA18()                                                 \
    asm volatile("s_waitcnt vmcnt(" #vmW_ ")" ::: "memory"); \
    __builtin_amdgcn_s_barrier();                            \
  }

  // prologue: stage tiles 0,1; ensure stage(0) landed block-wide
  STAGE(0, tiles[0])
  STAGE(1, tiles[1])
  asm volatile("s_waitcnt vmcnt(3)" ::: "memory");
  __builtin_amdgcn_s_barrier();

#pragma unroll 1
  for (int m = 0; m < 4; ++m) {  // kt = 0..11
    SLOT(3 * m + 0, tiles[0], tiles[2], true, 3)
    SLOT(3 * m + 1, tiles[1], tiles[0], true, 3)
    SLOT(3 * m + 2, tiles[2], tiles[1], true, 3)
  }
  SLOT(12, tiles[0], tiles[2], true, 3)   // stage(14)->b2
  SLOT(13, tiles[1], tiles[0], true, 3)   // stage(15)->b0
  SLOT(14, tiles[2], tiles[1], false, 0)  // drain stage(15)
  // kt=15 final: read b0, compute, no trailing sync needed before epilogue writes
  READ9(tiles[0])
  asm volatile("s_waitcnt lgkmcnt(0)" ::: "memory");
  __builtin_amdgcn_sched_barrier(0);
  MFMA18()
#undef STAGE
#undef READ9
#undef MFMA18
#undef SLOT

  // ---- epilogue: dual-axis max ----
  // C/D map (16x16): col X = wc*96 + fc*16 + l15, row Y = wr*48 + fr*16 + lhi*4 + r
#pragma unroll
  for (int fc = 0; fc < 6; ++fc) {
    float v = -3.4e38f;
#pragma unroll
    for (int fr = 0; fr < 3; ++fr)
#pragma unroll
      for (int r = 0; r < 4; ++r) v = fmaxf(v, acc[fr][fc][r]);
    v = fmaxf(v, __shfl_xor(v, 16));
    v = fmaxf(v, __shfl_xor(v, 32));
    if (lane < 16) colp[wr][wc * 96 + fc * 16 + lane] = v;
  }
#pragma unroll
  for (int fr = 0; fr < 3; ++fr)
#pragma unroll
    for (int r = 0; r < 4; ++r) {
      float rv = acc[fr][0][r];
#pragma unroll
      for (int fc = 1; fc < 6; ++fc) rv = fmaxf(rv, acc[fr][fc][r]);
      rv = fmaxf(rv, __shfl_xor(rv, 1));
      rv = fmaxf(rv, __shfl_xor(rv, 2));
      rv = fmaxf(rv, __shfl_xor(rv, 4));
      rv = fmaxf(rv, __shfl_xor(rv, 8));
      if (l15 == 0) rowpart[wc][wr * 48 + fr * 16 + lhi * 4 + r] = rv;
    }
  __syncthreads();

  // ---- fused BN -> fc dot -> logit BN -> sigmoid ----
  float partial = 0.f;
  if (t < HW) {
    const float rmax = fmaxf(rowpart[0][t], rowpart[1][t]);
    const float cmax =
        fmaxf(fmaxf(colp[0][t], colp[1][t]), fmaxf(colp[2][t], colp[3][t]));
    const float scale = bn_w[0] / sqrtf(bn_v[0] + EPSV);
    const float bm = bn_m[0], bb = bn_b[0];
    partial = ((cmax - bm) * scale + bb) * fc_w[t] +
              ((rmax - bm) * scale + bb) * fc_w[HW + t];
  }
#pragma unroll
  for (int off = 1; off < 64; off <<= 1) partial += __shfl_xor(partial, off);
  if (lane == 0) wsum[wid] = partial;
  __syncthreads();
  if (t == 0) {
    float sum = fc_b[0];
#pragma unroll
    for (int w = 0; w < 8; ++w) sum += wsum[w];
    const float logit = (sum - lbn_m[0]) * (lbn_w[0] / sqrtf(lbn_v[0] + EPSV)) + lbn_b[0];
    out[bid] = 1.f / (1.f + expf(-logit * 0.1f));
  }
}

// ---------------- naive f32 fallback (only if ws too small) ----------------
__global__ __launch_bounds__(256) void qaconv_naive(
    const float* __restrict__ gal, const float* __restrict__ prob,
    const float* __restrict__ bn_w, const float* __restrict__ bn_b,
    const float* __restrict__ bn_m, const float* __restrict__ bn_v,
    const float* __restrict__ fc_w, const float* __restrict__ fc_b,
    const float* __restrict__ lbn_w, const float* __restrict__ lbn_b,
    const float* __restrict__ lbn_m, const float* __restrict__ lbn_v,
    float* __restrict__ out) {
  __shared__ float prow[ND];
  __shared__ float rowmaxs[HW];
  __shared__ float colmaxs[HW];
  __shared__ float red[4];
  const int bid = blockIdx.x;
  const int g = bid >> 6, p = bid & 63;
  const int t = threadIdx.x, lane = t & 63, wid = t >> 6;
  const float* gp = gal + (size_t)g * ND * HW;
  const float* pp = prob + (size_t)p * ND * HW;
  float colmax = -3.4e38f;
  for (int y = 0; y < HW; ++y) {
    for (int k = t; k < ND; k += 256) prow[k] = pp[(size_t)k * HW + y];
    __syncthreads();
    float sv = -3.4e38f;
    if (t < HW) {
      sv = 0.f;
      for (int k = 0; k < ND; ++k) sv = fmaf(prow[k], gp[(size_t)k * HW + t], sv);
      colmax = fmaxf(colmax, sv);
    }
    float m = sv;
#pragma unroll
    for (int off = 1; off < 64; off <<= 1) m = fmaxf(m, __shfl_xor(m, off));
    if (lane == 0) red[wid] = m;
    __syncthreads();
    if (t == 0) rowmaxs[y] = fmaxf(fmaxf(red[0], red[1]), fmaxf(red[2], red[3]));
    __syncthreads();
  }
  if (t < HW) colmaxs[t] = colmax;
  __syncthreads();
  float partial = 0.f;
  for (int j = t; j < 2 * HW; j += 256) {
    const float v = (j < HW) ? colmaxs[j] : rowmaxs[j - HW];
    const float sc = (v - bn_m[0]) * (bn_w[0] / sqrtf(bn_v[0] + EPSV)) + bn_b[0];
    partial += sc * fc_w[j];
  }
#pragma unroll
  for (int off = 1; off < 64; off <<= 1) partial += __shfl_xor(partial, off);
  if (lane == 0) red[wid] = partial;
  __syncthreads();
  if (t == 0) {
    const float sum = fc_b[0] + red[0] + red[1] + red[2] + red[3];
    const float logit = (sum - lbn_m[0]) * (lbn_w[0] / sqrtf(lbn_v[0] + EPSV)) + lbn_b[0];
    out[bid] = 1.f / (1.f + expf(-logit * 0.1f));
  }
}

extern "C" void kernel_launch(void* const* d_in, const int* in_sizes, int n_in,
                              void* d_out, int out_size, void* d_ws, size_t ws_size,
                              hipStream_t stream) {
  const float* gal = (const float*)d_in[0];
  const float* prob = (const float*)d_in[1];
  const float* bn_w = (const float*)d_in[2];
  const float* bn_b = (const float*)d_in[3];
  const float* bn_m = (const float*)d_in[4];
  const float* bn_v = (const float*)d_in[5];
  const float* fc_w = (const float*)d_in[6];
  const float* fc_b = (const float*)d_in[7];
  const float* lbn_w = (const float*)d_in[8];
  const float* lbn_b = (const float*)d_in[9];
  const float* lbn_m = (const float*)d_in[10];
  const float* lbn_v = (const float*)d_in[11];
  float* out = (float*)d_out;

  const size_t probT5_elems = (size_t)NP * 98304;  // 6.29M halves
  const size_t galT5_elems = (size_t)NG * 98304;   // 3.15M halves
  const size_t ws_needed = (probT5_elems + galT5_elems) * sizeof(_Float16);
  if (ws_size >= ws_needed) {
    _Float16* probT5 = (_Float16*)d_ws;
    _Float16* galT5 = probT5 + probT5_elems;
    prep_frag5<<<dim3(NP + NG, KT16), dim3(256), 0, stream>>>(gal, prob, galT5, probT5);
    qaconv_main<<<dim3(NG * NP), dim3(512), 0, stream>>>(
        galT5, probT5, bn_w, bn_b, bn_m, bn_v, fc_w, fc_b, lbn_w, lbn_b, lbn_m, lbn_v, out);
  } else {
    qaconv_naive<<<dim3(NG * NP), dim3(256), 0, stream>>>(
        gal, prob, bn_w, bn_b, bn_m, bn_v, fc_w, fc_b, lbn_w, lbn_b, lbn_m, lbn_v, out);
  }
}